// Round 10
// baseline (39549.893 us; speedup 1.0000x reference)
//
#include <hip/hip_runtime.h>

#define T_N 512
#define B_N 32
#define H_N 512
#define G3 1536
#define NCMP 96
#define NBLK 97
#define NT 1024
#define EPS_LN 1e-5f
#define OUT_HID_OFF (T_N * B_N * 1024)
#define ZBID 16   // kind0, d0, jt=16: non-gate, hosts stats zeroer

// ws uint offsets (barrier region):
#define ARR_B10 0     // 96 flags: all blocks arrive after GEMM_0(s)
#define ARR_B11 128   // 96 flags: all blocks arrive after GEMM_1(s)
#define ARR_B20 256   // 16 flags: gates0 blocks arrive after gates(q=0,s)
#define ARR_B21 384   // 16 flags: gates1 blocks arrive after gates(q=1,s)
#define ARR_PH  512   // 96 flags: phase barrier
#define REL0    640   // + set*32; sets: 0=B10,1=B11,2=B20,3=B21,4=PH

// ws float offsets:
#define WS_STATS 832
#define STSLOT   768
#define WS_DOTS  (WS_STATS + 4 * STSLOT)          // [kd 4][b 32][j 1536]
#define WS_HBUF  (WS_DOTS + 4 * B_N * G3)          // [d 2][b 32][512]
#define WS_Y0    (WS_HBUF + 2 * B_N * H_N)         // [d 2][t 512][b 32][512]

// LDS (163072 B — proven): wlds 32256, hl 8256, sred 256
#define WLDS_F 32256
#define HL_F   8256
#define LDS_BYTES ((WLDS_F + HL_F + 256) * 4)

__device__ __forceinline__ float cload(const float* p) {
  return __hip_atomic_load(p, __ATOMIC_RELAXED, __HIP_MEMORY_SCOPE_AGENT);
}
__device__ __forceinline__ void cstore(float* p, float v) {
  __hip_atomic_store(p, v, __ATOMIC_RELAXED, __HIP_MEMORY_SCOPE_AGENT);
}
union U64F2 { unsigned long long u; float f[2]; };
__device__ __forceinline__ U64F2 cload2(const float* p) {
  U64F2 r;
  r.u = __hip_atomic_load((const unsigned long long*)p, __ATOMIC_RELAXED,
                          __HIP_MEMORY_SCOPE_AGENT);
  return r;
}

// Split barrier primitives (flags monotone; no reset).
__device__ __forceinline__ void barr_arrive(unsigned* arr, int idx, unsigned e) {
  __builtin_amdgcn_s_waitcnt(0);   // drain this wave's vmem (coherent stores at L3)
  __syncthreads();
  if (threadIdx.x == 0)
    __hip_atomic_store(arr + idx, e, __ATOMIC_RELAXED, __HIP_MEMORY_SCOPE_AGENT);
}
__device__ __forceinline__ void barr_wait(unsigned* rel, unsigned e) {
  if (threadIdx.x == 0) {
    while (__hip_atomic_load(rel, __ATOMIC_RELAXED, __HIP_MEMORY_SCOPE_AGENT) < e)
      __builtin_amdgcn_s_sleep(1);
  }
  __syncthreads();
}

// 16 FMAs: 2 j-weights (WA,WB) x 2 b-rows (R1,R2), componentwise (c = k&3).
#define FMA16(WA, WB, R1, R2) do { \
  acc[0][0][0]=fmaf((R1).x,(WA).x,acc[0][0][0]); acc[0][0][1]=fmaf((R1).y,(WA).y,acc[0][0][1]); \
  acc[0][0][2]=fmaf((R1).z,(WA).z,acc[0][0][2]); acc[0][0][3]=fmaf((R1).w,(WA).w,acc[0][0][3]); \
  acc[0][1][0]=fmaf((R2).x,(WA).x,acc[0][1][0]); acc[0][1][1]=fmaf((R2).y,(WA).y,acc[0][1][1]); \
  acc[0][1][2]=fmaf((R2).z,(WA).z,acc[0][1][2]); acc[0][1][3]=fmaf((R2).w,(WA).w,acc[0][1][3]); \
  acc[1][0][0]=fmaf((R1).x,(WB).x,acc[1][0][0]); acc[1][0][1]=fmaf((R1).y,(WB).y,acc[1][0][1]); \
  acc[1][0][2]=fmaf((R1).z,(WB).z,acc[1][0][2]); acc[1][0][3]=fmaf((R1).w,(WB).w,acc[1][0][3]); \
  acc[1][1][0]=fmaf((R2).x,(WB).x,acc[1][1][0]); acc[1][1][1]=fmaf((R2).y,(WB).y,acc[1][1][1]); \
  acc[1][1][2]=fmaf((R2).z,(WB).z,acc[1][1][2]); acc[1][1][3]=fmaf((R2).w,(WB).w,acc[1][1][3]); \
} while (0)

__global__ void __launch_bounds__(NT, 1)
lngru15(const float* __restrict__ x, const float* __restrict__ h0,
        const float* __restrict__ Wx, const float* __restrict__ Wh,
        const float* __restrict__ bx, const float* __restrict__ bh,
        const float* __restrict__ gx, const float* __restrict__ bex,
        const float* __restrict__ gh, const float* __restrict__ beh,
        float* __restrict__ out, float* __restrict__ ws)
{
  extern __shared__ __align__(16) float smem[];
  float* wlds = smem;                    // [k4 126][j 64][4]
  float* hl   = smem + WLDS_F;           // [b 16][516]  (time-shared h0/h1 tile)
  float* sred = smem + WLDS_F + HL_F;    // [b_loc 16][jq 4][2]

  unsigned* bu   = (unsigned*)ws;
  unsigned* rel  = bu + REL0;
  float* stats = ws + WS_STATS;
  float* dots  = ws + WS_DOTS;
  float* hbuf  = ws + WS_HBUF;
  float* y0    = ws + WS_Y0;

  const int tid  = threadIdx.x;
  const int bid  = blockIdx.x;

  // ---------------- collector block ----------------
  if (bid == NCMP) {
    unsigned e = 0;
    for (int ph = 0; ph < 2; ++ph) {
      unsigned pe = ph + 1u;
      if (tid < NCMP)
        while (__hip_atomic_load(bu + ARR_PH + tid, __ATOMIC_RELAXED, __HIP_MEMORY_SCOPE_AGENT) < pe)
          __builtin_amdgcn_s_sleep(1);
      __syncthreads();
      if (tid == 0) __hip_atomic_store(rel + 4*32, pe, __ATOMIC_RELAXED, __HIP_MEMORY_SCOPE_AGENT);
      for (int s = 0; s < T_N; ++s) {
        e++;
        if (tid < NCMP)
          while (__hip_atomic_load(bu + ARR_B10 + tid, __ATOMIC_RELAXED, __HIP_MEMORY_SCOPE_AGENT) < e)
            __builtin_amdgcn_s_sleep(1);
        __syncthreads();
        if (tid == 0) __hip_atomic_store(rel + 0*32, e, __ATOMIC_RELAXED, __HIP_MEMORY_SCOPE_AGENT);
        if (tid < NCMP)
          while (__hip_atomic_load(bu + ARR_B11 + tid, __ATOMIC_RELAXED, __HIP_MEMORY_SCOPE_AGENT) < e)
            __builtin_amdgcn_s_sleep(1);
        __syncthreads();
        if (tid == 0) __hip_atomic_store(rel + 1*32, e, __ATOMIC_RELAXED, __HIP_MEMORY_SCOPE_AGENT);
        if (tid < 16)
          while (__hip_atomic_load(bu + ARR_B20 + tid, __ATOMIC_RELAXED, __HIP_MEMORY_SCOPE_AGENT) < e)
            __builtin_amdgcn_s_sleep(1);
        __syncthreads();
        if (tid == 0) __hip_atomic_store(rel + 2*32, e, __ATOMIC_RELAXED, __HIP_MEMORY_SCOPE_AGENT);
        if (tid < 16)
          while (__hip_atomic_load(bu + ARR_B21 + tid, __ATOMIC_RELAXED, __HIP_MEMORY_SCOPE_AGENT) < e)
            __builtin_amdgcn_s_sleep(1);
        __syncthreads();
        if (tid == 0) __hip_atomic_store(rel + 3*32, e, __ATOMIC_RELAXED, __HIP_MEMORY_SCOPE_AGENT);
      }
    }
    return;
  }

  // ---------------- compute blocks ----------------
  const int lane = tid & 63;
  const int wv   = tid >> 6;              // 16 waves
  const int jt   = bid % 24;              // 64-wide j tile
  const int kd   = bid / 24;              // d*2 + kind
  const int kind = kd & 1;                // 0: ax, 1: ah
  const int d    = kd >> 1;
  const int j0   = jt * 64;
  const int g    = jt >> 3;               // gate of this j-tile
  const bool gates0 = (kind == 0) && (jt < 8);                 // q=0 gate owners
  const bool gates1 = (kind == 0) && (jt >= 8) && (jt < 16);   // q=1 gate owners
  const int ct   = gates0 ? jt : (jt - 8);                     // gate c-tile
  const int gidx = d * 8 + ct;                                 // 0..15 per set

  // GEMM (r3/r7-proven): 4 waves (wv<4); lane = (boct 8)x(jj 8);
  // lane tile 2j x 2b: j in {j0+jq*8+jj, +32}, b in {q*16+boct, +8}, full K.
  const bool gw  = (wv < 4);
  const int jq   = wv & 3;
  const int jj   = lane & 7;
  const int boct = lane >> 3;
  const int jla  = jq * 8 + jj;
  const int jlb  = jla + 32;

  for (int ph = 0; ph < 2; ++ph) {
    const int widx = ph * 2 + d;
    const unsigned pe = ph + 1u;

    // ---- stage weights: k<504 -> LDS, k>=504 -> gw-lane tail regs ----
    const float* wgl = (kind ? Wh : Wx) + (size_t)widx * H_N * G3 + j0;
    for (int kk = 0; kk < 32; ++kk) {
      int k = wv * 32 + kk;
      if (k < 504)
        wlds[(k >> 2) * 256 + lane * 4 + (k & 3)] = wgl[(size_t)k * G3 + lane];
    }
    float4 wt[2][2];
    float  bva = 0.f, bvb = 0.f;
    if (gw) {
      bva = (kind ? bh : bx)[widx * G3 + j0 + jla];
      bvb = (kind ? bh : bx)[widx * G3 + j0 + jlb];
#pragma unroll
      for (int h = 0; h < 2; ++h) {
        wt[0][h].x = wgl[(size_t)(504 + 4*h + 0) * G3 + jla];
        wt[0][h].y = wgl[(size_t)(504 + 4*h + 1) * G3 + jla];
        wt[0][h].z = wgl[(size_t)(504 + 4*h + 2) * G3 + jla];
        wt[0][h].w = wgl[(size_t)(504 + 4*h + 3) * G3 + jla];
        wt[1][h].x = wgl[(size_t)(504 + 4*h + 0) * G3 + jlb];
        wt[1][h].y = wgl[(size_t)(504 + 4*h + 1) * G3 + jlb];
        wt[1][h].z = wgl[(size_t)(504 + 4*h + 2) * G3 + jlb];
        wt[1][h].w = wgl[(size_t)(504 + 4*h + 3) * G3 + jlb];
      }
    }
    if (kind) {   // hl <- h0 rows 0..15 (q=0 initial)
#pragma unroll
      for (int q4 = 0; q4 < 8; ++q4)
        hl[wv * 516 + lane + 64*q4] =
            h0[((size_t)widx * B_N + wv) * H_N + lane + 64*q4];
    }
    if (gates0) {  // hbuf rows 0..15, cols ct*64..+64 <- h0
      cstore(&hbuf[(d * B_N + wv) * H_N + ct*64 + lane],
             h0[((size_t)widx * B_N + wv) * H_N + ct*64 + lane]);
    }
    if (gates1) {  // hbuf rows 16..31
      cstore(&hbuf[(d * B_N + 16 + wv) * H_N + ct*64 + lane],
             h0[((size_t)widx * B_N + 16 + wv) * H_N + ct*64 + lane]);
    }
    if (ph == 1 && bid == ZBID) {   // re-zero all stats slots for phase 1
      for (int i = tid; i < 4 * STSLOT; i += NT) cstore(stats + i, 0.f);
    }
    barr_arrive(bu + ARR_PH, bid, pe);
    barr_wait(rel + 4*32, pe);

    const float* xsrc = (ph == 0) ? x : (y0 + (size_t)d * T_N * B_N * H_N);
    const float4* wqa = (const float4*)wlds + jla;
    const float4* wqb = (const float4*)wlds + jlb;
    const float*  h1  = hl + boct * 516;
    const float*  h2  = hl + (boct + 8) * 516;

    // GEMM + dots + stats for half q, step ss
    auto run_gemm = [&](int q, int ss) {
      float acc[2][2][4] = {{{0.f,0.f,0.f,0.f},{0.f,0.f,0.f,0.f}},
                            {{0.f,0.f,0.f,0.f},{0.f,0.f,0.f,0.f}}};
      if (gw) {
        if (kind) {
#pragma unroll 3
          for (int k4 = 0; k4 < 126; ++k4) {
            float4 wa = wqa[k4 * 64];
            float4 wb = wqb[k4 * 64];
            float4 r1 = *(const float4*)(h1 + k4 * 4);
            float4 r2 = *(const float4*)(h2 + k4 * 4);
            FMA16(wa, wb, r1, r2);
          }
          float4 r1a = *(const float4*)(h1 + 504);
          float4 r1b = *(const float4*)(h1 + 508);
          float4 r2a = *(const float4*)(h2 + 504);
          float4 r2b = *(const float4*)(h2 + 508);
          FMA16(wt[0][0], wt[1][0], r1a, r2a);
          FMA16(wt[0][1], wt[1][1], r1b, r2b);
        } else {
          const int t = d ? (T_N - 1 - ss) : ss;
          const float* rp1 = xsrc + ((size_t)t * B_N + q*16 + boct) * H_N;
          const float* rp2 = rp1 + 8 * H_N;
#pragma unroll 6
          for (int k4 = 0; k4 < 126; ++k4) {
            float4 wa = wqa[k4 * 64];
            float4 wb = wqb[k4 * 64];
            float4 r1 = *(const float4*)(rp1 + k4 * 4);
            float4 r2 = *(const float4*)(rp2 + k4 * 4);
            FMA16(wa, wb, r1, r2);
          }
          float4 r1a = *(const float4*)(rp1 + 504);
          float4 r1b = *(const float4*)(rp1 + 508);
          float4 r2a = *(const float4*)(rp2 + 504);
          float4 r2b = *(const float4*)(rp2 + 508);
          FMA16(wt[0][0], wt[1][0], r1a, r2a);
          FMA16(wt[0][1], wt[1][1], r1b, r2b);
        }
        float ta1 = bva + (acc[0][0][0] + acc[0][0][1]) + (acc[0][0][2] + acc[0][0][3]);
        float ta2 = bva + (acc[0][1][0] + acc[0][1][1]) + (acc[0][1][2] + acc[0][1][3]);
        float tb1 = bvb + (acc[1][0][0] + acc[1][0][1]) + (acc[1][0][2] + acc[1][0][3]);
        float tb2 = bvb + (acc[1][1][0] + acc[1][1][1]) + (acc[1][1][2] + acc[1][1][3]);

        float* dr1 = dots + (size_t)(kd * B_N + q*16 + boct) * G3 + j0;
        float* dr2 = dr1 + (size_t)8 * G3;
        cstore(dr1 + jla, ta1);
        cstore(dr1 + jlb, tb1);
        cstore(dr2 + jla, ta2);
        cstore(dr2 + jlb, tb2);

        float s1a = ta1 + tb1, s2a = ta1 * ta1 + tb1 * tb1;
        float s1b = ta2 + tb2, s2b = ta2 * ta2 + tb2 * tb2;
        s1a += __shfl_xor(s1a, 1, 64); s2a += __shfl_xor(s2a, 1, 64);
        s1b += __shfl_xor(s1b, 1, 64); s2b += __shfl_xor(s2b, 1, 64);
        s1a += __shfl_xor(s1a, 2, 64); s2a += __shfl_xor(s2a, 2, 64);
        s1b += __shfl_xor(s1b, 2, 64); s2b += __shfl_xor(s2b, 2, 64);
        s1a += __shfl_xor(s1a, 4, 64); s2a += __shfl_xor(s2a, 4, 64);
        s1b += __shfl_xor(s1b, 4, 64); s2b += __shfl_xor(s2b, 4, 64);
        if (jj == 0) {
          sred[(boct * 4 + jq) * 2 + 0] = s1a;
          sred[(boct * 4 + jq) * 2 + 1] = s2a;
          sred[((boct + 8) * 4 + jq) * 2 + 0] = s1b;
          sred[((boct + 8) * 4 + jq) * 2 + 1] = s2b;
        }
      }
      __syncthreads();
      if (tid < 32) {
        int bl = tid >> 1, st = tid & 1;
        float a2 = 0.f;
#pragma unroll
        for (int qq = 0; qq < 4; ++qq) a2 += sred[(bl * 4 + qq) * 2 + st];
        atomicAdd(&stats[(size_t)(ss & 3) * STSLOT +
                         ((kd * 3 + g) * B_N + q*16 + bl) * 2 + st], a2);
      }
    };

    // gates for half q, c-tile ct, step ss: compute h, write hbuf + y0/out
    auto run_gates = [&](int q, int ss) {
      const int t  = d ? (T_N - 1 - ss) : ss;
      const int gb = q*16 + wv;
      const int c  = ct * 64 + lane;
      const float* stp = stats + (size_t)(ss & 3) * STSLOT;
      float a[2][3];
#pragma unroll
      for (int k2 = 0; k2 < 2; ++k2) {
        const float* dr  = dots + (size_t)((d * 2 + k2) * B_N + gb) * G3;
        const float* gam = (k2 ? gh : gx) + widx * G3;
        const float* bet = (k2 ? beh : bex) + widx * G3;
#pragma unroll
        for (int g2 = 0; g2 < 3; ++g2) {
          float v = cload(dr + g2 * H_N + c);
          const float* sl = stp + (((d * 2 + k2) * 3 + g2) * B_N + gb) * 2;
          float mu  = cload(sl)     * (1.f / 512.f);
          float var = cload(sl + 1) * (1.f / 512.f) - mu * mu;
          float inv = rsqrtf(var + EPS_LN);
          int J = g2 * H_N + c;
          a[k2][g2] = (v - mu) * inv * gam[J] + bet[J];
        }
      }
      float r = 1.f / (1.f + __expf(-(a[0][0] + a[1][0])));
      float z = 1.f / (1.f + __expf(-(a[0][1] + a[1][1])));
      float n = tanhf(a[0][2] + r * a[1][2]);
      float* hp = hbuf + (size_t)(d * B_N + gb) * H_N + c;
      float hnew = (1.f - z) * n + z * cload(hp);
      cstore(hp, hnew);
      if (ph == 0)
        cstore(&y0[(((size_t)d * T_N + t) * B_N + gb) * H_N + c], hnew);
      else
        out[((size_t)t * B_N + gb) * 1024 + d * H_N + c] = hnew;
      if (ss == T_N - 1)
        out[OUT_HID_OFF + ((size_t)widx * B_N + gb) * H_N + c] = hnew;
    };

    auto stage_h = [&](int q) {   // hl <- hbuf rows q*16..q*16+15 (coherent)
      const float* hsrc = hbuf + (size_t)(d * B_N + q*16) * H_N;
#pragma unroll
      for (int q4 = 0; q4 < 4; ++q4) {
        int e2 = (tid + q4 * 1024) * 2;
        U64F2 v = cload2(hsrc + e2);
        int bb = e2 >> 9, k = e2 & 511;
        hl[bb * 516 + k]     = v.f[0];
        hl[bb * 516 + k + 1] = v.f[1];
      }
      __syncthreads();
    };

    for (int s = 0; s < T_N; ++s) {
      const unsigned e = (unsigned)(ph * T_N + s + 1);

      run_gemm(0, s);                       // half 0 (hl holds h0(s-1) for kind1)
      barr_arrive(bu + ARR_B10, bid, e);

      if (kind) stage_h(1);                 // hl <- h1(s-1)
      else if (bid == ZBID) {               // zero stats slot (s+2)&3
        if (tid < STSLOT) cstore(stats + (size_t)((s + 2) & 3) * STSLOT + tid, 0.f);
      }

      run_gemm(1, s);                       // half 1
      barr_arrive(bu + ARR_B11, bid, e);

      if (gates0) {
        barr_wait(rel + 0*32, e);           // dots/stats(q=0) visible
        run_gates(0, s);
        barr_arrive(bu + ARR_B20, gidx, e);
      }
      if (gates1) {
        barr_wait(rel + 1*32, e);           // dots/stats(q=1) visible
        run_gates(1, s);
        barr_arrive(bu + ARR_B21, gidx, e);
      }

      barr_wait(rel + 2*32, e);             // h0(s) published
      if (kind) stage_h(0);                 // hl <- h0(s) for next GEMM_0
      barr_wait(rel + 3*32, e);             // h1(s) published (next stage_h(1))
    }
  }
}

extern "C" void kernel_launch(void* const* d_in, const int* in_sizes, int n_in,
                              void* d_out, int out_size, void* d_ws, size_t ws_size,
                              hipStream_t stream) {
  const float* x    = (const float*)d_in[0];
  const float* h0   = (const float*)d_in[1];
  const float* Wx   = (const float*)d_in[2];
  const float* Wh   = (const float*)d_in[3];
  const float* bxp  = (const float*)d_in[4];
  const float* bhp  = (const float*)d_in[5];
  const float* gxp  = (const float*)d_in[6];
  const float* bexp = (const float*)d_in[7];
  const float* ghp  = (const float*)d_in[8];
  const float* behp = (const float*)d_in[9];
  float* out = (float*)d_out;
  float* ws  = (float*)d_ws;

  hipMemsetAsync(d_ws, 0, 16384, stream);   // flags + releases + stats ring

  hipFuncSetAttribute((const void*)lngru15,
                      hipFuncAttributeMaxDynamicSharedMemorySize, LDS_BYTES);

  void* args[] = {(void*)&x, (void*)&h0, (void*)&Wx, (void*)&Wh, (void*)&bxp, (void*)&bhp,
                  (void*)&gxp, (void*)&bexp, (void*)&ghp, (void*)&behp, (void*)&out, (void*)&ws};
  hipLaunchCooperativeKernel((void*)lngru15, dim3(NBLK), dim3(NT), args, LDS_BYTES, stream);
}